// Round 19
// baseline (64.233 us; speedup 1.0000x reference)
//
#include <hip/hip_runtime.h>

// DCNv2 fused: deformable im2col + f16 MFMA GEMM.
// R19: R18's main K-loop byte-identical (the verified 40us configuration:
//      lb(256,2), VGPR=128, depth-2 pipeline). Aux restructured:
//      K1 prep = transpose_x + transpose_w + out:=bias (fused, 1 launch)
//      K2 main = k-split x2, epilogue atomicAdd into out (no parts/reduce).
// ws: [0, 8388608)       xt  = x transposed to (n, hw, C) f16
//     [8388608, 9568256) wt2 = weight tiled [f][q][r][kq] f16

typedef _Float16 f16x8 __attribute__((ext_vector_type(8)));
typedef _Float16 f16x4 __attribute__((ext_vector_type(4)));
typedef float f32x4 __attribute__((ext_vector_type(4)));

#define C_IN 256
#define CO   256
#define KK   9
#define HWSZ 4096
#define LDB  72        // sB row stride (elems)
#define BUFB (64 * LDB)

struct __align__(16) SP2 { uint4 off; f16x4 w; };   // 32 B

static __device__ __forceinline__ f16x8 splat8(_Float16 v) {
    f16x8 r = {v, v, v, v, v, v, v, v};
    return r;
}

// ---- K1 prep: [0,1024) transpose_x | [1024,1280) transpose_w | rest: out=bias
__global__ void prep_kernel(const float* __restrict__ x,
                            const float* __restrict__ w,
                            const float* __restrict__ bias,
                            _Float16* __restrict__ xt,
                            _Float16* __restrict__ wt2,
                            float* __restrict__ out) {
    __shared__ float tile[64][65];
    const int b = blockIdx.x;
    if (b < 1024) {
        const int bx = b & 63, by = (b >> 6) & 3, n = b >> 8;
        const int p0 = bx * 64;
        const int c0 = by * 64;
        const int tx = threadIdx.x & 63;
        const int ty = threadIdx.x >> 6;
        for (int i = 0; i < 16; ++i) {
            int c = ty * 16 + i;
            tile[c][tx] = x[((size_t)(n * C_IN + c0 + c) << 12) + p0 + tx];
        }
        __syncthreads();
        for (int i = 0; i < 16; ++i) {
            int p = ty * 16 + i;
            xt[((size_t)((n << 12) + p0 + p) << 8) + c0 + tx] =
                (_Float16)tile[tx][p];
        }
    } else if (b < 1280) {
        const int o = b - 1024;
        const int c = threadIdx.x;
        const int f = o >> 4, r = o & 15, cc = c >> 5, kq = c & 31;
        for (int kk = 0; kk < KK; ++kk) {
            int q = cc * 9 + kk;
            wt2[((f * 72 + q) * 16 + r) * 32 + kq] =
                (_Float16)w[(o * C_IN + c) * KK + kk];
        }
    } else {
        // out init: 4*256*4096 f32 = 1,048,576 f32x4 -> 4096 blocks
        const int i = (b - 1280) * 256 + threadIdx.x;   // f32x4 index
        const float bv = bias[(i >> 10) & 255];
        ((f32x4*)out)[i] = (f32x4){bv, bv, bv, bv};
    }
}

// ---- fused main: block = 256 Co x 64 pix x K-half, 4 waves (1 M-slab each) --
__launch_bounds__(256, 2)
__global__ void dcn_main_kernel(const float* __restrict__ offset,
                                const float* __restrict__ mask,
                                const _Float16* __restrict__ xt,
                                const _Float16* __restrict__ wt2,
                                float* __restrict__ out) {
    constexpr int NS = 18;              // K-steps of 64 (k-half)
    __shared__ SP2 sP[576];
    __shared__ _Float16 sB[2][BUFB];

    const int tid = threadIdx.x;
    const int lin = blockIdx.x;
    const int id  = (lin & 7) * 64 + (lin >> 3);    // XCD-contiguous work ids
    const int half = id >> 8;
    const int pt   = id & 255;
    const int p0   = pt * 64;
    const int n    = p0 >> 12;
    const int phw0 = p0 & 4095;
    const int cc0  = half * 4;

    // --- precompute bilinear params: 64 pixels x 9 taps ---
    for (int t = tid; t < 576; t += 256) {
        int pl = t / 9;
        int k  = t - pl * 9;
        int phw = phw0 + pl;
        int h = phw >> 6, w = phw & 63;
        float dy = offset[(size_t)(n * 18 + 2 * k)     * HWSZ + phw];
        float dx = offset[(size_t)(n * 18 + 2 * k + 1) * HWSZ + phw];
        float mv = mask  [(size_t)(n * 9 + k)          * HWSZ + phw];
        float py = dy + (float)(h - 1 + k / 3);
        float px = dx + (float)(w - 1 + k % 3);
        float y0f = floorf(py), x0f = floorf(px);
        int y0 = (int)y0f, x0 = (int)x0f;
        float wy1 = py - y0f, wx1 = px - x0f;
        float wy0 = 1.f - wy1, wx0 = 1.f - wx1;
        int y1 = y0 + 1, x1 = x0 + 1;
        float vy0 = (y0 >= 0 && y0 < 64) ? 1.f : 0.f;
        float vy1 = (y1 >= 0 && y1 < 64) ? 1.f : 0.f;
        float vx0 = (x0 >= 0 && x0 < 64) ? 1.f : 0.f;
        float vx1 = (x1 >= 0 && x1 < 64) ? 1.f : 0.f;
        int cy0 = min(max(y0, 0), 63), cy1 = min(max(y1, 0), 63);
        int cx0 = min(max(x0, 0), 63), cx1 = min(max(x1, 0), 63);
        SP2 e;
        e.off = make_uint4((unsigned)(cy0 * 64 + cx0) << 9,
                           (unsigned)(cy0 * 64 + cx1) << 9,
                           (unsigned)(cy1 * 64 + cx0) << 9,
                           (unsigned)(cy1 * 64 + cx1) << 9);
        f16x4 wv;
        wv.x = (_Float16)(wy0 * wx0 * mv * vy0 * vx0);
        wv.y = (_Float16)(wy0 * wx1 * mv * vy0 * vx1);
        wv.z = (_Float16)(wy1 * wx0 * mv * vy1 * vx0);
        wv.w = (_Float16)(wy1 * wx1 * mv * vy1 * vx1);
        e.w = wv;
        sP[t] = e;
    }
    __syncthreads();

    const int lane = tid & 63;
    const int wid  = tid >> 6;   // 0..3 = M slab (64 Co each)
    const int l15  = lane & 15;
    const int lhi  = lane >> 4;

    const int pixl  = tid >> 2;  // staging pixel 0..63
    const int oct   = tid & 3;   // staging c-octet
    const int pixl9 = pixl * 9;

    const char* xb  = (const char*)(xt + ((size_t)n << 12) * C_IN);
    const char* wtb = (const char*)wt2;

    const int vBe = l15 * LDB + lhi * 8;               // + fn*16*LDB in macro
    const int vWe = pixl * LDB + oct * 8;              // B-write elem base
    const unsigned chBase = (unsigned)(cc0 * 64 + oct * 16);

    unsigned voffA[4];
    for (int fm = 0; fm < 4; ++fm) {
        int fglob = wid * 4 + fm;
        voffA[fm] = (unsigned)((fglob * 72 + cc0 * 9) * 1024 + l15 * 64 + lhi * 16);
    }

    f16x8 ga[2][8];   // gather corners, slot = feeding-step & 1 (2-deep)
    f16x8 aa[2][8];   // A fragments,   slot = feeding-step & 1 (1-deep ahead)
    f16x4 gw[2][2];
    f32x4 acc[4][4];
    for (int i = 0; i < 4; ++i)
        for (int j = 0; j < 4; ++j)
            acc[i][j] = (f32x4){0.f, 0.f, 0.f, 0.f};

// T = step the data feeds; all %9, /9 fold under full unroll.
#define ISSUE_GA(T, SLOT)                                                     \
    {                                                                         \
        const SP2 e0 = sP[pixl9 + (2 * (T)) % 9];                             \
        const SP2 e1 = sP[pixl9 + (2 * (T) + 1) % 9];                         \
        gw[SLOT][0] = e0.w;                                                   \
        gw[SLOT][1] = e1.w;                                                   \
        const unsigned cE = chBase + (unsigned)(((2 * (T)) / 9) * 64);        \
        const unsigned cO = chBase + (unsigned)(((2 * (T) + 1) / 9) * 64);    \
        ga[SLOT][0] = *(const f16x8*)(xb + (e0.off.x + cE));                  \
        ga[SLOT][1] = *(const f16x8*)(xb + (e0.off.y + cE));                  \
        ga[SLOT][2] = *(const f16x8*)(xb + (e0.off.z + cE));                  \
        ga[SLOT][3] = *(const f16x8*)(xb + (e0.off.w + cE));                  \
        ga[SLOT][4] = *(const f16x8*)(xb + (e1.off.x + cO));                  \
        ga[SLOT][5] = *(const f16x8*)(xb + (e1.off.y + cO));                  \
        ga[SLOT][6] = *(const f16x8*)(xb + (e1.off.z + cO));                  \
        ga[SLOT][7] = *(const f16x8*)(xb + (e1.off.w + cO));                  \
    }

#define ISSUE_A(T, SLOT)                                                      \
    {                                                                         \
        for (int fm_ = 0; fm_ < 4; ++fm_) {                                   \
            unsigned vo_ = voffA[fm_] + (unsigned)((T) * 2048);               \
            aa[SLOT][fm_ * 2 + 0] = *(const f16x8*)(wtb + vo_);               \
            aa[SLOT][fm_ * 2 + 1] = *(const f16x8*)(wtb + vo_ + 1024);        \
        }                                                                     \
    }

#define COMBINE(SLOT, BUF)                                                    \
    {                                                                         \
        _Float16* bw_ = &sB[0][0] + (BUF) * BUFB + vWe;                       \
        f16x8 r0_ = ga[SLOT][0] * splat8(gw[SLOT][0].x)                       \
                  + ga[SLOT][1] * splat8(gw[SLOT][0].y)                       \
                  + ga[SLOT][2] * splat8(gw[SLOT][0].z)                       \
                  + ga[SLOT][3] * splat8(gw[SLOT][0].w);                      \
        f16x8 r1_ = ga[SLOT][4] * splat8(gw[SLOT][1].x)                       \
                  + ga[SLOT][5] * splat8(gw[SLOT][1].y)                       \
                  + ga[SLOT][6] * splat8(gw[SLOT][1].z)                       \
                  + ga[SLOT][7] * splat8(gw[SLOT][1].w);                      \
        *(f16x8*)(bw_)      = r0_;                                            \
        *(f16x8*)(bw_ + 32) = r1_;                                            \
    }

#define MFMA_STEP(SLOT, BUF)                                                  \
    {                                                                         \
        const _Float16* br_ = &sB[0][0] + (BUF) * BUFB + vBe;                 \
        for (int fn_ = 0; fn_ < 4; ++fn_) {                                   \
            f16x8 bE_ = *(const f16x8*)(br_ + fn_ * 16 * LDB);                \
            f16x8 bO_ = *(const f16x8*)(br_ + fn_ * 16 * LDB + 32);           \
            for (int fm_ = 0; fm_ < 4; ++fm_) {                               \
                acc[fm_][fn_] = __builtin_amdgcn_mfma_f32_16x16x32_f16(       \
                    aa[SLOT][fm_ * 2 + 0], bE_, acc[fm_][fn_], 0, 0, 0);      \
                acc[fm_][fn_] = __builtin_amdgcn_mfma_f32_16x16x32_f16(       \
                    aa[SLOT][fm_ * 2 + 1], bO_, acc[fm_][fn_], 0, 0, 0);      \
            }                                                                 \
        }                                                                     \
    }

#define BAR()                                                                 \
    {                                                                         \
        asm volatile("s_waitcnt lgkmcnt(0)" ::: "memory");                    \
        __builtin_amdgcn_s_barrier();                                         \
        asm volatile("" ::: "memory");                                        \
    }

    // prologue: GA(0), GA(1) in flight; A(0); COMBINE(0) waits only GA(0).
    ISSUE_GA(0, 0)
    ISSUE_GA(1, 1)
    ISSUE_A(0, 0)
    COMBINE(0, 0)
    BAR()

#pragma unroll
    for (int s = 0; s < NS; ++s) {
        if (s + 1 < NS) ISSUE_A(s + 1, (s + 1) & 1)   // feeds MFMA(s+1)
        if (s + 2 < NS) ISSUE_GA(s + 2, s & 1)        // feeds COMBINE(s+2)
        __builtin_amdgcn_sched_barrier(0);            // pin issues above uses
        MFMA_STEP(s & 1, s & 1)                       // vmcnt leaves 24 flying
        if (s + 1 < NS) {
            COMBINE((s + 1) & 1, (s + 1) & 1)         // vmcnt leaves 16 flying
            BAR()
        }
    }

    // --- epilogue: atomic accumulate into out (pre-inited with bias) ---
    // C/D layout col=lane&15 (pix), row=(lane>>4)*4+r (o)
    for (int fm = 0; fm < 4; ++fm)
        for (int fn = 0; fn < 4; ++fn) {
            int pix = phw0 + fn * 16 + l15;
            for (int r = 0; r < 4; ++r) {
                int o = wid * 64 + fm * 16 + lhi * 4 + r;
                atomicAdd(&out[((size_t)(n * CO + o) << 12) + pix],
                          acc[fm][fn][r]);
            }
        }
#undef ISSUE_GA
#undef ISSUE_A
#undef COMBINE
#undef MFMA_STEP
#undef BAR
}

extern "C" void kernel_launch(void* const* d_in, const int* in_sizes, int n_in,
                              void* d_out, int out_size, void* d_ws, size_t ws_size,
                              hipStream_t stream) {
    const float* x      = (const float*)d_in[0];
    const float* offset = (const float*)d_in[1];
    const float* mask   = (const float*)d_in[2];
    const float* weight = (const float*)d_in[3];
    const float* bias   = (const float*)d_in[4];
    float* out = (float*)d_out;

    _Float16* xt  = (_Float16*)d_ws;
    _Float16* wt2 = (_Float16*)((char*)d_ws + 8388608);

    // K1: transpose_x (1024 blocks) + transpose_w (256) + out=bias (4096)
    prep_kernel<<<dim3(1024 + 256 + 4096), 256, 0, stream>>>(x, weight, bias,
                                                             xt, wt2, out);
    // K2: fused main, k-split x2, atomic epilogue
    dcn_main_kernel<<<dim3(512), 256, 0, stream>>>(offset, mask, xt, wt2, out);
}

// Round 20
// 51.294 us; speedup vs baseline: 1.2522x; 1.2522x over previous
//
#include <hip/hip_runtime.h>

// DCNv2 fused: deformable im2col + f16 MFMA GEMM.
// R20 = R18 (verified 53.56 us) with transpose_x + transpose_w fused into one
//   prep launch. Main loop byte-identical: 256Co x 64pix x K-half blocks,
//   4 waves, depth-2 gather pipeline, counted-wait barriers, lb(256,2)
//   (VGPR=128 — the only non-spilling, non-sinking config found in R1-R19),
//   f16 partials + fused reduce(+bias). Atomic epilogue (R19) REVERTED: +14us.
// ws: [0, 8388608)            xt  = x transposed to (n, hw, C) f16
//     [8388608, 9568256)      wt2 = weight tiled [f][q][r][kq] f16
//     [9568256, +2*8388608)   parts[2] = k-half partial sums f16

typedef _Float16 f16x8 __attribute__((ext_vector_type(8)));
typedef _Float16 f16x4 __attribute__((ext_vector_type(4)));
typedef float f32x4 __attribute__((ext_vector_type(4)));

#define C_IN 256
#define CO   256
#define KK   9
#define HWSZ 4096
#define LDB  72        // sB row stride (elems)
#define BUFB (64 * LDB)
#define PSTR (4 * CO * HWSZ)

struct __align__(16) SP2 { uint4 off; f16x4 w; };   // 32 B

static __device__ __forceinline__ f16x8 splat8(_Float16 v) {
    f16x8 r = {v, v, v, v, v, v, v, v};
    return r;
}

// ---- prep: [0,1024) transpose_x | [1024,1280) transpose_w ----
__global__ void prep_kernel(const float* __restrict__ x,
                            const float* __restrict__ w,
                            _Float16* __restrict__ xt,
                            _Float16* __restrict__ wt2) {
    __shared__ float tile[64][65];
    const int b = blockIdx.x;
    if (b < 1024) {
        const int bx = b & 63, by = (b >> 6) & 3, n = b >> 8;
        const int p0 = bx * 64;
        const int c0 = by * 64;
        const int tx = threadIdx.x & 63;
        const int ty = threadIdx.x >> 6;
        for (int i = 0; i < 16; ++i) {
            int c = ty * 16 + i;
            tile[c][tx] = x[((size_t)(n * C_IN + c0 + c) << 12) + p0 + tx];
        }
        __syncthreads();
        for (int i = 0; i < 16; ++i) {
            int p = ty * 16 + i;
            xt[((size_t)((n << 12) + p0 + p) << 8) + c0 + tx] =
                (_Float16)tile[tx][p];
        }
    } else {
        const int o = b - 1024;
        const int c = threadIdx.x;
        const int f = o >> 4, r = o & 15, cc = c >> 5, kq = c & 31;
        for (int kk = 0; kk < KK; ++kk) {
            int q = cc * 9 + kk;
            wt2[((f * 72 + q) * 16 + r) * 32 + kq] =
                (_Float16)w[(o * C_IN + c) * KK + kk];
        }
    }
}

// ---- fused main: block = 256 Co x 64 pix x K-half, 4 waves (1 M-slab each) --
__launch_bounds__(256, 2)
__global__ void dcn_main_kernel(const float* __restrict__ offset,
                                const float* __restrict__ mask,
                                const _Float16* __restrict__ xt,
                                const _Float16* __restrict__ wt2,
                                _Float16* __restrict__ parts) {
    constexpr int NS = 18;              // K-steps of 64 (k-half)
    __shared__ SP2 sP[576];
    __shared__ _Float16 sB[2][BUFB];

    const int tid = threadIdx.x;
    const int lin = blockIdx.x;
    const int id  = (lin & 7) * 64 + (lin >> 3);    // XCD-contiguous work ids
    const int half = id >> 8;
    const int pt   = id & 255;
    const int p0   = pt * 64;
    const int n    = p0 >> 12;
    const int phw0 = p0 & 4095;
    const int cc0  = half * 4;

    // --- precompute bilinear params: 64 pixels x 9 taps ---
    for (int t = tid; t < 576; t += 256) {
        int pl = t / 9;
        int k  = t - pl * 9;
        int phw = phw0 + pl;
        int h = phw >> 6, w = phw & 63;
        float dy = offset[(size_t)(n * 18 + 2 * k)     * HWSZ + phw];
        float dx = offset[(size_t)(n * 18 + 2 * k + 1) * HWSZ + phw];
        float mv = mask  [(size_t)(n * 9 + k)          * HWSZ + phw];
        float py = dy + (float)(h - 1 + k / 3);
        float px = dx + (float)(w - 1 + k % 3);
        float y0f = floorf(py), x0f = floorf(px);
        int y0 = (int)y0f, x0 = (int)x0f;
        float wy1 = py - y0f, wx1 = px - x0f;
        float wy0 = 1.f - wy1, wx0 = 1.f - wx1;
        int y1 = y0 + 1, x1 = x0 + 1;
        float vy0 = (y0 >= 0 && y0 < 64) ? 1.f : 0.f;
        float vy1 = (y1 >= 0 && y1 < 64) ? 1.f : 0.f;
        float vx0 = (x0 >= 0 && x0 < 64) ? 1.f : 0.f;
        float vx1 = (x1 >= 0 && x1 < 64) ? 1.f : 0.f;
        int cy0 = min(max(y0, 0), 63), cy1 = min(max(y1, 0), 63);
        int cx0 = min(max(x0, 0), 63), cx1 = min(max(x1, 0), 63);
        SP2 e;
        e.off = make_uint4((unsigned)(cy0 * 64 + cx0) << 9,
                           (unsigned)(cy0 * 64 + cx1) << 9,
                           (unsigned)(cy1 * 64 + cx0) << 9,
                           (unsigned)(cy1 * 64 + cx1) << 9);
        f16x4 wv;
        wv.x = (_Float16)(wy0 * wx0 * mv * vy0 * vx0);
        wv.y = (_Float16)(wy0 * wx1 * mv * vy0 * vx1);
        wv.z = (_Float16)(wy1 * wx0 * mv * vy1 * vx0);
        wv.w = (_Float16)(wy1 * wx1 * mv * vy1 * vx1);
        e.w = wv;
        sP[t] = e;
    }
    __syncthreads();

    const int lane = tid & 63;
    const int wid  = tid >> 6;   // 0..3 = M slab (64 Co each)
    const int l15  = lane & 15;
    const int lhi  = lane >> 4;

    const int pixl  = tid >> 2;  // staging pixel 0..63
    const int oct   = tid & 3;   // staging c-octet
    const int pixl9 = pixl * 9;

    const char* xb  = (const char*)(xt + ((size_t)n << 12) * C_IN);
    const char* wtb = (const char*)wt2;

    const int vBe = l15 * LDB + lhi * 8;               // + fn*16*LDB in macro
    const int vWe = pixl * LDB + oct * 8;              // B-write elem base
    const unsigned chBase = (unsigned)(cc0 * 64 + oct * 16);

    unsigned voffA[4];
    for (int fm = 0; fm < 4; ++fm) {
        int fglob = wid * 4 + fm;
        voffA[fm] = (unsigned)((fglob * 72 + cc0 * 9) * 1024 + l15 * 64 + lhi * 16);
    }

    f16x8 ga[2][8];   // gather corners, slot = feeding-step & 1 (2-deep)
    f16x8 aa[2][8];   // A fragments,   slot = feeding-step & 1 (1-deep ahead)
    f16x4 gw[2][2];
    f32x4 acc[4][4];
    for (int i = 0; i < 4; ++i)
        for (int j = 0; j < 4; ++j)
            acc[i][j] = (f32x4){0.f, 0.f, 0.f, 0.f};

// T = step the data feeds; all %9, /9 fold under full unroll.
#define ISSUE_GA(T, SLOT)                                                     \
    {                                                                         \
        const SP2 e0 = sP[pixl9 + (2 * (T)) % 9];                             \
        const SP2 e1 = sP[pixl9 + (2 * (T) + 1) % 9];                         \
        gw[SLOT][0] = e0.w;                                                   \
        gw[SLOT][1] = e1.w;                                                   \
        const unsigned cE = chBase + (unsigned)(((2 * (T)) / 9) * 64);        \
        const unsigned cO = chBase + (unsigned)(((2 * (T) + 1) / 9) * 64);    \
        ga[SLOT][0] = *(const f16x8*)(xb + (e0.off.x + cE));                  \
        ga[SLOT][1] = *(const f16x8*)(xb + (e0.off.y + cE));                  \
        ga[SLOT][2] = *(const f16x8*)(xb + (e0.off.z + cE));                  \
        ga[SLOT][3] = *(const f16x8*)(xb + (e0.off.w + cE));                  \
        ga[SLOT][4] = *(const f16x8*)(xb + (e1.off.x + cO));                  \
        ga[SLOT][5] = *(const f16x8*)(xb + (e1.off.y + cO));                  \
        ga[SLOT][6] = *(const f16x8*)(xb + (e1.off.z + cO));                  \
        ga[SLOT][7] = *(const f16x8*)(xb + (e1.off.w + cO));                  \
    }

#define ISSUE_A(T, SLOT)                                                      \
    {                                                                         \
        for (int fm_ = 0; fm_ < 4; ++fm_) {                                   \
            unsigned vo_ = voffA[fm_] + (unsigned)((T) * 2048);               \
            aa[SLOT][fm_ * 2 + 0] = *(const f16x8*)(wtb + vo_);               \
            aa[SLOT][fm_ * 2 + 1] = *(const f16x8*)(wtb + vo_ + 1024);        \
        }                                                                     \
    }

#define COMBINE(SLOT, BUF)                                                    \
    {                                                                         \
        _Float16* bw_ = &sB[0][0] + (BUF) * BUFB + vWe;                       \
        f16x8 r0_ = ga[SLOT][0] * splat8(gw[SLOT][0].x)                       \
                  + ga[SLOT][1] * splat8(gw[SLOT][0].y)                       \
                  + ga[SLOT][2] * splat8(gw[SLOT][0].z)                       \
                  + ga[SLOT][3] * splat8(gw[SLOT][0].w);                      \
        f16x8 r1_ = ga[SLOT][4] * splat8(gw[SLOT][1].x)                       \
                  + ga[SLOT][5] * splat8(gw[SLOT][1].y)                       \
                  + ga[SLOT][6] * splat8(gw[SLOT][1].z)                       \
                  + ga[SLOT][7] * splat8(gw[SLOT][1].w);                      \
        *(f16x8*)(bw_)      = r0_;                                            \
        *(f16x8*)(bw_ + 32) = r1_;                                            \
    }

#define MFMA_STEP(SLOT, BUF)                                                  \
    {                                                                         \
        const _Float16* br_ = &sB[0][0] + (BUF) * BUFB + vBe;                 \
        for (int fn_ = 0; fn_ < 4; ++fn_) {                                   \
            f16x8 bE_ = *(const f16x8*)(br_ + fn_ * 16 * LDB);                \
            f16x8 bO_ = *(const f16x8*)(br_ + fn_ * 16 * LDB + 32);           \
            for (int fm_ = 0; fm_ < 4; ++fm_) {                               \
                acc[fm_][fn_] = __builtin_amdgcn_mfma_f32_16x16x32_f16(       \
                    aa[SLOT][fm_ * 2 + 0], bE_, acc[fm_][fn_], 0, 0, 0);      \
                acc[fm_][fn_] = __builtin_amdgcn_mfma_f32_16x16x32_f16(       \
                    aa[SLOT][fm_ * 2 + 1], bO_, acc[fm_][fn_], 0, 0, 0);      \
            }                                                                 \
        }                                                                     \
    }

#define BAR()                                                                 \
    {                                                                         \
        asm volatile("s_waitcnt lgkmcnt(0)" ::: "memory");                    \
        __builtin_amdgcn_s_barrier();                                         \
        asm volatile("" ::: "memory");                                        \
    }

    // prologue: GA(0), GA(1) in flight; A(0); COMBINE(0) waits only GA(0).
    ISSUE_GA(0, 0)
    ISSUE_GA(1, 1)
    ISSUE_A(0, 0)
    COMBINE(0, 0)
    BAR()

#pragma unroll
    for (int s = 0; s < NS; ++s) {
        if (s + 1 < NS) ISSUE_A(s + 1, (s + 1) & 1)   // feeds MFMA(s+1)
        if (s + 2 < NS) ISSUE_GA(s + 2, s & 1)        // feeds COMBINE(s+2)
        __builtin_amdgcn_sched_barrier(0);            // pin issues above uses
        MFMA_STEP(s & 1, s & 1)                       // vmcnt leaves 24 flying
        if (s + 1 < NS) {
            COMBINE((s + 1) & 1, (s + 1) & 1)         // vmcnt leaves 16 flying
            BAR()
        }
    }

    // --- epilogue: C/D layout col=lane&15 (pix), row=(lane>>4)*4+r (o) ---
    _Float16* pp = parts + (size_t)half * PSTR;
    for (int fm = 0; fm < 4; ++fm)
        for (int fn = 0; fn < 4; ++fn) {
            int pix = phw0 + fn * 16 + l15;
            for (int r = 0; r < 4; ++r) {
                int o = wid * 64 + fm * 16 + lhi * 4 + r;
                pp[((size_t)(n * CO + o) << 12) + pix] =
                    (_Float16)acc[fm][fn][r];
            }
        }
#undef ISSUE_GA
#undef ISSUE_A
#undef COMBINE
#undef MFMA_STEP
#undef BAR
}

// ---- reduce: out = parts[0] + parts[1] + bias ----
__global__ void reduce_kernel(float* __restrict__ out,
                              const _Float16* __restrict__ parts,
                              const float* __restrict__ bias, int n8) {
    int i = blockIdx.x * blockDim.x + threadIdx.x;
    if (i >= n8) return;
    f16x8 a = ((const f16x8*)parts)[i];
    f16x8 b = ((const f16x8*)(parts + (size_t)PSTR))[i];
    float bv = bias[((i * 8) >> 12) & 255];
    f32x4 r0, r1;
    for (int e = 0; e < 4; ++e)
        r0[e] = (float)a[e] + (float)b[e] + bv;
    for (int e = 0; e < 4; ++e)
        r1[e] = (float)a[e + 4] + (float)b[e + 4] + bv;
    ((f32x4*)out)[2 * i]     = r0;
    ((f32x4*)out)[2 * i + 1] = r1;
}

extern "C" void kernel_launch(void* const* d_in, const int* in_sizes, int n_in,
                              void* d_out, int out_size, void* d_ws, size_t ws_size,
                              hipStream_t stream) {
    const float* x      = (const float*)d_in[0];
    const float* offset = (const float*)d_in[1];
    const float* mask   = (const float*)d_in[2];
    const float* weight = (const float*)d_in[3];
    const float* bias   = (const float*)d_in[4];
    float* out = (float*)d_out;

    _Float16* xt  = (_Float16*)d_ws;
    _Float16* wt2 = (_Float16*)((char*)d_ws + 8388608);
    _Float16* parts = (_Float16*)((char*)d_ws + 9568256);

    prep_kernel<<<dim3(1280), 256, 0, stream>>>(x, weight, xt, wt2);
    dcn_main_kernel<<<dim3(512), 256, 0, stream>>>(offset, mask, xt, wt2, parts);
    reduce_kernel<<<dim3(PSTR / 8 / 256), 256, 0, stream>>>(out, parts, bias,
                                                            PSTR / 8);
}